// Round 1
// baseline (454.803 us; speedup 1.0000x reference)
//
#include <hip/hip_runtime.h>
#include <math.h>

#define NNODES 50000
#define NEDGES 800000
#define NF 128
constexpr float LN_EPS = 1e-5f;

__device__ __forceinline__ float clean0(float v) {
    // nan->0, +inf->0, -inf->0
    return (isnan(v) || isinf(v)) ? 0.0f : v;
}
__device__ __forceinline__ float cleanw(float v) {
    // nan->0, +inf->1, -inf->0
    if (isnan(v)) return 0.0f;
    if (isinf(v)) return v > 0.0f ? 1.0f : 0.0f;
    return v;
}
__device__ __forceinline__ int clampN(int v) {
    return min(max(v, 0), NNODES - 1);
}

// ---- init: deg=1 (self loop weight), counters=0 -------------------------
__global__ void k_init(float* deg, int* cnt, int* fill) {
    int i = blockIdx.x * blockDim.x + threadIdx.x;
    if (i < NNODES) { deg[i] = 1.0f; cnt[i] = 0; fill[i] = 0; }
}

// ---- per-edge: clean weight, accumulate degree + in-degree count --------
__global__ void k_edge_prep(const int* __restrict__ ei, const float* __restrict__ ea,
                            float* __restrict__ ew, float* __restrict__ deg,
                            int* __restrict__ cnt) {
    int e = blockIdx.x * blockDim.x + threadIdx.x;
    if (e >= NEDGES) return;
    int c = clampN(ei[NEDGES + e]);
    float w = cleanw(ea[e]);
    ew[e] = w;
    atomicAdd(&deg[c], w);
    atomicAdd(&cnt[c], 1);
}

// ---- deg -> dis = rsqrt(deg) in place -----------------------------------
__global__ void k_dis(float* deg) {
    int i = blockIdx.x * blockDim.x + threadIdx.x;
    if (i < NNODES) {
        float d = deg[i];
        deg[i] = (d > 0.0f) ? rsqrtf(d) : 0.0f;
    }
}

// ---- 3-kernel exclusive scan of cnt[N] -> rowptr[N+1] -------------------
__global__ void k_scan1(const int* __restrict__ cnt, int* __restrict__ bsum) {
    __shared__ int sm[256];
    int t = threadIdx.x;
    int i = blockIdx.x * 256 + t;
    sm[t] = (i < NNODES) ? cnt[i] : 0;
    __syncthreads();
    for (int o = 128; o > 0; o >>= 1) {
        if (t < o) sm[t] += sm[t + o];
        __syncthreads();
    }
    if (t == 0) bsum[blockIdx.x] = sm[0];
}

__global__ void k_scan2(int* __restrict__ bsum, int nb) {
    __shared__ int sm[256];
    int t = threadIdx.x;
    int v = (t < nb) ? bsum[t] : 0;
    sm[t] = v;
    __syncthreads();
    for (int o = 1; o < 256; o <<= 1) {
        int add = (t >= o) ? sm[t - o] : 0;
        __syncthreads();
        sm[t] += add;
        __syncthreads();
    }
    if (t < nb) bsum[t] = sm[t] - v;   // exclusive
}

__global__ void k_scan3(const int* __restrict__ cnt, const int* __restrict__ bsum,
                        int* __restrict__ rowptr) {
    __shared__ int sm[256];
    int t = threadIdx.x;
    int i = blockIdx.x * 256 + t;
    int v = (i < NNODES) ? cnt[i] : 0;
    sm[t] = v;
    __syncthreads();
    for (int o = 1; o < 256; o <<= 1) {
        int add = (t >= o) ? sm[t - o] : 0;
        __syncthreads();
        sm[t] += add;
        __syncthreads();
    }
    if (i < NNODES) rowptr[i + 1] = bsum[blockIdx.x] + sm[t];  // inclusive + base
    if (i == 0) rowptr[0] = 0;
}

// ---- scatter edges into CSR (by target) ---------------------------------
__global__ void k_csr_fill(const int* __restrict__ ei, const float* __restrict__ ew,
                           const float* __restrict__ dis, const int* __restrict__ rowptr,
                           int* __restrict__ fill, int* __restrict__ csr_src,
                           float* __restrict__ csr_norm) {
    int e = blockIdx.x * blockDim.x + threadIdx.x;
    if (e >= NEDGES) return;
    int r = clampN(ei[e]);
    int c = clampN(ei[NEDGES + e]);
    int pos = rowptr[c] + atomicAdd(&fill[c], 1);
    csr_src[pos] = r;
    csr_norm[pos] = dis[r] * ew[e] * dis[c];
}

// ---- LayerNorm: one wave per node, float2 per lane ----------------------
__global__ void k_layernorm(const float* __restrict__ x, const float* __restrict__ gamma,
                            const float* __restrict__ beta, float* __restrict__ xn) {
    int n = (blockIdx.x * blockDim.x + threadIdx.x) >> 6;
    int lane = threadIdx.x & 63;
    if (n >= NNODES) return;
    float2 v = ((const float2*)(x + (size_t)n * NF))[lane];
    v.x = clean0(v.x); v.y = clean0(v.y);
    float s = v.x + v.y;
    for (int o = 32; o > 0; o >>= 1) s += __shfl_xor(s, o);
    float mu = s * (1.0f / NF);
    float dx = v.x - mu, dy = v.y - mu;
    float q = dx * dx + dy * dy;
    for (int o = 32; o > 0; o >>= 1) q += __shfl_xor(q, o);
    float rstd = rsqrtf(q * (1.0f / NF) + LN_EPS);
    float2 g = ((const float2*)gamma)[lane];
    float2 b = ((const float2*)beta)[lane];
    float2 o2;
    o2.x = dx * rstd * g.x + b.x;
    o2.y = dy * rstd * g.y + b.y;
    ((float2*)(xn + (size_t)n * NF))[lane] = o2;
}

// ---- fp32 GEMM: C[M,128] = A[M,128] @ W[128,128] ------------------------
// 64-row tile per block, W staged in 32-row k-chunks (LDS 49.4 KB -> 3 blk/CU)
__global__ __launch_bounds__(256) void k_gemm128(const float* __restrict__ A,
                                                 const float* __restrict__ W,
                                                 float* __restrict__ C, int M) {
    __shared__ float xs[64][129];   // +1 pad: rows 8 apart land on different banks
    __shared__ float ws[32][128];
    int t = threadIdx.x;
    int row0 = blockIdx.x * 64;

    // stage x-tile (64x128), coalesced float4
    for (int i = 0; i < 8; i++) {
        int j = t + i * 256;          // float4 slot 0..2047
        int r = j >> 5;
        int c4 = (j & 31) * 4;
        int gr = row0 + r;
        float4 v = make_float4(0.f, 0.f, 0.f, 0.f);
        if (gr < M) v = *(const float4*)(A + (size_t)gr * 128 + c4);
        xs[r][c4 + 0] = v.x; xs[r][c4 + 1] = v.y; xs[r][c4 + 2] = v.z; xs[r][c4 + 3] = v.w;
    }

    int tx = t & 31, ty = t >> 5;
    int c0 = tx * 4, r0 = ty * 8;
    float acc[8][4];
    #pragma unroll
    for (int j = 0; j < 8; j++)
        for (int q = 0; q < 4; q++) acc[j][q] = 0.0f;

    for (int kk = 0; kk < 4; kk++) {
        __syncthreads();
        // stage 32 k-rows of W
        for (int i = 0; i < 4; i++) {
            int j = t + i * 256;       // float4 slot 0..1023
            int r = j >> 5;
            int c4 = (j & 31) * 4;
            *(float4*)&ws[r][c4] = *(const float4*)(W + (size_t)(kk * 32 + r) * 128 + c4);
        }
        __syncthreads();
        #pragma unroll
        for (int k2 = 0; k2 < 32; k2++) {
            float4 wv = *(const float4*)&ws[k2][c0];
            int kg = kk * 32 + k2;
            #pragma unroll
            for (int j = 0; j < 8; j++) {
                float a = xs[r0 + j][kg];
                acc[j][0] += a * wv.x;
                acc[j][1] += a * wv.y;
                acc[j][2] += a * wv.z;
                acc[j][3] += a * wv.w;
            }
        }
    }

    #pragma unroll
    for (int j = 0; j < 8; j++) {
        int gr = row0 + r0 + j;
        if (gr < M) {
            float4 v = make_float4(acc[j][0], acc[j][1], acc[j][2], acc[j][3]);
            *(float4*)(C + (size_t)gr * 128 + c0) = v;
        }
    }
}

// ---- CSR aggregation: one wave per node, float2 per lane ----------------
template <bool RELU>
__global__ void k_aggregate(const float* __restrict__ h, const float* __restrict__ dis,
                            const int* __restrict__ rowptr, const int* __restrict__ csr_src,
                            const float* __restrict__ csr_norm, const float* __restrict__ bias,
                            float* __restrict__ out) {
    int n = (blockIdx.x * blockDim.x + threadIdx.x) >> 6;
    int lane = threadIdx.x & 63;
    if (n >= NNODES) return;
    float d = dis[n];
    float sn = d * d;                       // self-loop norm
    float2 acc = ((const float2*)(h + (size_t)n * NF))[lane];
    acc.x *= sn; acc.y *= sn;
    int beg = rowptr[n], end = rowptr[n + 1];
    for (int base = beg; base < end; base += 64) {
        int idx = base + lane;
        int s = 0; float w = 0.0f;
        if (idx < end) { s = csr_src[idx]; w = csr_norm[idx]; }
        int cnt = min(64, end - base);
        for (int j = 0; j < cnt; j++) {
            int sj = __shfl(s, j);
            float wj = __shfl(w, j);
            float2 hv = *(const float2*)(h + (size_t)sj * NF + 2 * lane);
            acc.x += hv.x * wj;
            acc.y += hv.y * wj;
        }
    }
    float2 b = ((const float2*)bias)[lane];
    acc.x += b.x; acc.y += b.y;
    if (RELU) { acc.x = fmaxf(acc.x, 0.0f); acc.y = fmaxf(acc.y, 0.0f); }
    ((float2*)(out + (size_t)n * NF))[lane] = acc;
}

// ---- GEMV: h3[n] = dot(X[n,:], W3[:,0]) ---------------------------------
__global__ void k_gemv128(const float* __restrict__ X, const float* __restrict__ W3,
                          float* __restrict__ h3) {
    int n = (blockIdx.x * blockDim.x + threadIdx.x) >> 6;
    int lane = threadIdx.x & 63;
    if (n >= NNODES) return;
    float2 v = ((const float2*)(X + (size_t)n * NF))[lane];
    float2 w = ((const float2*)W3)[lane];
    float s = v.x * w.x + v.y * w.y;
    for (int o = 32; o > 0; o >>= 1) s += __shfl_xor(s, o);
    if (lane == 0) h3[n] = s;
}

// ---- scalar aggregation for output layer --------------------------------
__global__ void k_agg_scalar(const float* __restrict__ h3, const float* __restrict__ dis,
                             const int* __restrict__ rowptr, const int* __restrict__ csr_src,
                             const float* __restrict__ csr_norm, const float* __restrict__ b3,
                             float* __restrict__ out) {
    int n = blockIdx.x * blockDim.x + threadIdx.x;
    if (n >= NNODES) return;
    float d = dis[n];
    float acc = h3[n] * d * d;
    int beg = rowptr[n], end = rowptr[n + 1];
    for (int i = beg; i < end; i++) acc += h3[csr_src[i]] * csr_norm[i];
    out[n] = acc + b3[0];
}

extern "C" void kernel_launch(void* const* d_in, const int* in_sizes, int n_in,
                              void* d_out, int out_size, void* d_ws, size_t ws_size,
                              hipStream_t stream) {
    const float* x  = (const float*)d_in[0];
    const int*   ei = (const int*)d_in[1];
    const float* ea = (const float*)d_in[2];
    const float* g  = (const float*)d_in[3];
    const float* be = (const float*)d_in[4];
    const float* W1 = (const float*)d_in[5];
    const float* b1 = (const float*)d_in[6];
    const float* W2 = (const float*)d_in[7];
    const float* b2 = (const float*)d_in[8];
    const float* W3 = (const float*)d_in[9];
    const float* b3 = (const float*)d_in[10];
    float* out = (float*)d_out;

    char* ws = (char*)d_ws;
    size_t off = 0;
    auto alloc = [&](size_t bytes) {
        void* p = ws + off;
        off += (bytes + 255) & ~((size_t)255);
        return p;
    };
    float* bufA     = (float*)alloc((size_t)NNODES * NF * 4);
    float* bufB     = (float*)alloc((size_t)NNODES * NF * 4);
    float* bufC     = (float*)alloc((size_t)NNODES * NF * 4);
    float* ew       = (float*)alloc((size_t)NEDGES * 4);
    float* dis      = (float*)alloc((size_t)NNODES * 4);   // deg, then rsqrt in place
    int*   cnt      = (int*)  alloc((size_t)NNODES * 4);
    int*   rowptr   = (int*)  alloc((size_t)(NNODES + 1) * 4);
    int*   fill     = (int*)  alloc((size_t)NNODES * 4);
    int*   csr_src  = (int*)  alloc((size_t)NEDGES * 4);
    float* csr_norm = (float*)alloc((size_t)NEDGES * 4);
    int*   bsum     = (int*)  alloc(256 * 4);
    float* h3       = (float*)alloc((size_t)NNODES * 4);
    (void)ws_size; (void)in_sizes; (void)n_in; (void)out_size;

    const int NB_N = (NNODES + 255) / 256;      // 196
    const int NB_E = (NEDGES + 255) / 256;      // 3125
    const int NB_W = (NNODES * 64 + 255) / 256; // 12500 (wave per node)
    const int NB_G = (NNODES + 63) / 64;        // 782  (gemm 64-row tiles)

    k_init<<<NB_N, 256, 0, stream>>>(dis, cnt, fill);
    k_edge_prep<<<NB_E, 256, 0, stream>>>(ei, ea, ew, dis, cnt);
    k_scan1<<<NB_N, 256, 0, stream>>>(cnt, bsum);
    k_scan2<<<1, 256, 0, stream>>>(bsum, NB_N);
    k_scan3<<<NB_N, 256, 0, stream>>>(cnt, bsum, rowptr);
    k_dis<<<NB_N, 256, 0, stream>>>(dis);
    k_csr_fill<<<NB_E, 256, 0, stream>>>(ei, ew, dis, rowptr, fill, csr_src, csr_norm);

    k_layernorm<<<NB_W, 256, 0, stream>>>(x, g, be, bufA);

    // layer 1
    k_gemm128<<<NB_G, 256, 0, stream>>>(bufA, W1, bufB, NNODES);
    k_aggregate<true><<<NB_W, 256, 0, stream>>>(bufB, dis, rowptr, csr_src, csr_norm, b1, bufC);
    // layer 2
    k_gemm128<<<NB_G, 256, 0, stream>>>(bufC, W2, bufA, NNODES);
    k_aggregate<true><<<NB_W, 256, 0, stream>>>(bufA, dis, rowptr, csr_src, csr_norm, b2, bufB);
    // layer 3
    k_gemv128<<<NB_W, 256, 0, stream>>>(bufB, W3, h3);
    k_agg_scalar<<<NB_N, 256, 0, stream>>>(h3, dis, rowptr, csr_src, csr_norm, b3, out);
}

// Round 2
// 397.135 us; speedup vs baseline: 1.1452x; 1.1452x over previous
//
#include <hip/hip_runtime.h>
#include <math.h>

#define NNODES 50000
#define NEDGES 800000
#define NF 128
constexpr float LN_EPS = 1e-5f;

__device__ __forceinline__ float clean0(float v) {
    return (isnan(v) || isinf(v)) ? 0.0f : v;
}
__device__ __forceinline__ float cleanw(float v) {
    if (isnan(v)) return 0.0f;
    if (isinf(v)) return v > 0.0f ? 1.0f : 0.0f;
    return v;
}
__device__ __forceinline__ int clampN(int v) {
    return min(max(v, 0), NNODES - 1);
}

// ---- init: cnt=0 ---------------------------------------------------------
__global__ void k_init(int* cnt) {
    int i = blockIdx.x * blockDim.x + threadIdx.x;
    if (i < NNODES) cnt[i] = 0;
}

// ---- pass 1: clean weight, count in-degree, record per-edge rank ---------
// ONE atomic per edge (was two). rank makes the scatter pass atomic-free.
__global__ void k_count_rank(const int* __restrict__ ei, const float* __restrict__ ea,
                             float* __restrict__ ew, int* __restrict__ rank,
                             int* __restrict__ cnt) {
    int e = blockIdx.x * blockDim.x + threadIdx.x;
    if (e >= NEDGES) return;
    int c = clampN(ei[NEDGES + e]);
    ew[e] = cleanw(ea[e]);
    rank[e] = atomicAdd(&cnt[c], 1);
}

// ---- 3-kernel exclusive scan of cnt[N] -> rowptr[N+1] --------------------
__global__ void k_scan1(const int* __restrict__ cnt, int* __restrict__ bsum) {
    __shared__ int sm[256];
    int t = threadIdx.x;
    int i = blockIdx.x * 256 + t;
    sm[t] = (i < NNODES) ? cnt[i] : 0;
    __syncthreads();
    for (int o = 128; o > 0; o >>= 1) {
        if (t < o) sm[t] += sm[t + o];
        __syncthreads();
    }
    if (t == 0) bsum[blockIdx.x] = sm[0];
}

__global__ void k_scan2(int* __restrict__ bsum, int nb) {
    __shared__ int sm[256];
    int t = threadIdx.x;
    int v = (t < nb) ? bsum[t] : 0;
    sm[t] = v;
    __syncthreads();
    for (int o = 1; o < 256; o <<= 1) {
        int add = (t >= o) ? sm[t - o] : 0;
        __syncthreads();
        sm[t] += add;
        __syncthreads();
    }
    if (t < nb) bsum[t] = sm[t] - v;   // exclusive
}

__global__ void k_scan3(const int* __restrict__ cnt, const int* __restrict__ bsum,
                        int* __restrict__ rowptr) {
    __shared__ int sm[256];
    int t = threadIdx.x;
    int i = blockIdx.x * 256 + t;
    int v = (i < NNODES) ? cnt[i] : 0;
    sm[t] = v;
    __syncthreads();
    for (int o = 1; o < 256; o <<= 1) {
        int add = (t >= o) ? sm[t - o] : 0;
        __syncthreads();
        sm[t] += add;
        __syncthreads();
    }
    if (i < NNODES) rowptr[i + 1] = bsum[blockIdx.x] + sm[t];  // inclusive + base
    if (i == 0) rowptr[0] = 0;
}

// ---- pass 2: atomic-free scatter into CSR, packed (src, w) 8B ------------
__global__ void k_scatter(const int* __restrict__ ei, const float* __restrict__ ew,
                          const int* __restrict__ rank, const int* __restrict__ rowptr,
                          int2* __restrict__ csr_sw) {
    int e = blockIdx.x * blockDim.x + threadIdx.x;
    if (e >= NEDGES) return;
    int r = clampN(ei[e]);
    int c = clampN(ei[NEDGES + e]);
    int pos = rowptr[c] + rank[e];
    csr_sw[pos] = make_int2(r, __float_as_int(ew[e]));
}

// ---- deg by row-gather (no atomics), dis = rsqrt(deg) --------------------
__global__ void k_deg_dis(const int2* __restrict__ csr_sw, const int* __restrict__ rowptr,
                          float* __restrict__ dis) {
    int n = blockIdx.x * blockDim.x + threadIdx.x;
    if (n >= NNODES) return;
    int beg = rowptr[n], end = rowptr[n + 1];
    float d = 1.0f;                      // self-loop weight
    for (int p = beg; p < end; p++) d += __int_as_float(csr_sw[p].y);
    dis[n] = (d > 0.0f) ? rsqrtf(d) : 0.0f;
}

// ---- csr_norm packed (src, dis[src]*w*dis[n]) ----------------------------
__global__ void k_csr_norm(const int2* __restrict__ csr_sw, const int* __restrict__ rowptr,
                           const float* __restrict__ dis, int2* __restrict__ csr_sn) {
    int n = blockIdx.x * blockDim.x + threadIdx.x;
    if (n >= NNODES) return;
    int beg = rowptr[n], end = rowptr[n + 1];
    float dn = dis[n];
    for (int p = beg; p < end; p++) {
        int2 sw = csr_sw[p];
        float nm = dis[sw.x] * __int_as_float(sw.y) * dn;
        csr_sn[p] = make_int2(sw.x, __float_as_int(nm));
    }
}

// ---- LayerNorm: one wave per node, float2 per lane -----------------------
__global__ void k_layernorm(const float* __restrict__ x, const float* __restrict__ gamma,
                            const float* __restrict__ beta, float* __restrict__ xn) {
    int n = (blockIdx.x * blockDim.x + threadIdx.x) >> 6;
    int lane = threadIdx.x & 63;
    if (n >= NNODES) return;
    float2 v = ((const float2*)(x + (size_t)n * NF))[lane];
    v.x = clean0(v.x); v.y = clean0(v.y);
    float s = v.x + v.y;
    for (int o = 32; o > 0; o >>= 1) s += __shfl_xor(s, o);
    float mu = s * (1.0f / NF);
    float dx = v.x - mu, dy = v.y - mu;
    float q = dx * dx + dy * dy;
    for (int o = 32; o > 0; o >>= 1) q += __shfl_xor(q, o);
    float rstd = rsqrtf(q * (1.0f / NF) + LN_EPS);
    float2 g = ((const float2*)gamma)[lane];
    float2 b = ((const float2*)beta)[lane];
    float2 o2;
    o2.x = dx * rstd * g.x + b.x;
    o2.y = dy * rstd * g.y + b.y;
    ((float2*)(xn + (size_t)n * NF))[lane] = o2;
}

// ---- fp32 GEMM: C[M,128] = A[M,128] @ W[128,128] -------------------------
__global__ __launch_bounds__(256) void k_gemm128(const float* __restrict__ A,
                                                 const float* __restrict__ W,
                                                 float* __restrict__ C, int M) {
    __shared__ float xs[64][129];
    __shared__ float ws[32][128];
    int t = threadIdx.x;
    int row0 = blockIdx.x * 64;

    for (int i = 0; i < 8; i++) {
        int j = t + i * 256;
        int r = j >> 5;
        int c4 = (j & 31) * 4;
        int gr = row0 + r;
        float4 v = make_float4(0.f, 0.f, 0.f, 0.f);
        if (gr < M) v = *(const float4*)(A + (size_t)gr * 128 + c4);
        xs[r][c4 + 0] = v.x; xs[r][c4 + 1] = v.y; xs[r][c4 + 2] = v.z; xs[r][c4 + 3] = v.w;
    }

    int tx = t & 31, ty = t >> 5;
    int c0 = tx * 4, r0 = ty * 8;
    float acc[8][4];
    #pragma unroll
    for (int j = 0; j < 8; j++)
        for (int q = 0; q < 4; q++) acc[j][q] = 0.0f;

    for (int kk = 0; kk < 4; kk++) {
        __syncthreads();
        for (int i = 0; i < 4; i++) {
            int j = t + i * 256;
            int r = j >> 5;
            int c4 = (j & 31) * 4;
            *(float4*)&ws[r][c4] = *(const float4*)(W + (size_t)(kk * 32 + r) * 128 + c4);
        }
        __syncthreads();
        #pragma unroll
        for (int k2 = 0; k2 < 32; k2++) {
            float4 wv = *(const float4*)&ws[k2][c0];
            int kg = kk * 32 + k2;
            #pragma unroll
            for (int j = 0; j < 8; j++) {
                float a = xs[r0 + j][kg];
                acc[j][0] += a * wv.x;
                acc[j][1] += a * wv.y;
                acc[j][2] += a * wv.z;
                acc[j][3] += a * wv.w;
            }
        }
    }

    #pragma unroll
    for (int j = 0; j < 8; j++) {
        int gr = row0 + r0 + j;
        if (gr < M) {
            float4 v = make_float4(acc[j][0], acc[j][1], acc[j][2], acc[j][3]);
            *(float4*)(C + (size_t)gr * 128 + c0) = v;
        }
    }
}

// ---- CSR aggregation: one wave per node, float2 per lane -----------------
template <bool RELU>
__global__ void k_aggregate(const float* __restrict__ h, const float* __restrict__ dis,
                            const int* __restrict__ rowptr, const int2* __restrict__ csr_sn,
                            const float* __restrict__ bias, float* __restrict__ out) {
    int n = (blockIdx.x * blockDim.x + threadIdx.x) >> 6;
    int lane = threadIdx.x & 63;
    if (n >= NNODES) return;
    float d = dis[n];
    float sn = d * d;
    float2 acc = ((const float2*)(h + (size_t)n * NF))[lane];
    acc.x *= sn; acc.y *= sn;
    int beg = rowptr[n], end = rowptr[n + 1];
    for (int base = beg; base < end; base += 64) {
        int idx = base + lane;
        int s = 0; float w = 0.0f;
        if (idx < end) {
            int2 sn2 = csr_sn[idx];
            s = sn2.x; w = __int_as_float(sn2.y);
        }
        int cnt = min(64, end - base);
        for (int j = 0; j < cnt; j++) {
            int sj = __shfl(s, j);
            float wj = __shfl(w, j);
            float2 hv = *(const float2*)(h + (size_t)sj * NF + 2 * lane);
            acc.x += hv.x * wj;
            acc.y += hv.y * wj;
        }
    }
    float2 b = ((const float2*)bias)[lane];
    acc.x += b.x; acc.y += b.y;
    if (RELU) { acc.x = fmaxf(acc.x, 0.0f); acc.y = fmaxf(acc.y, 0.0f); }
    ((float2*)(out + (size_t)n * NF))[lane] = acc;
}

// ---- GEMV: h3[n] = dot(X[n,:], W3[:,0]) ----------------------------------
__global__ void k_gemv128(const float* __restrict__ X, const float* __restrict__ W3,
                          float* __restrict__ h3) {
    int n = (blockIdx.x * blockDim.x + threadIdx.x) >> 6;
    int lane = threadIdx.x & 63;
    if (n >= NNODES) return;
    float2 v = ((const float2*)(X + (size_t)n * NF))[lane];
    float2 w = ((const float2*)W3)[lane];
    float s = v.x * w.x + v.y * w.y;
    for (int o = 32; o > 0; o >>= 1) s += __shfl_xor(s, o);
    if (lane == 0) h3[n] = s;
}

// ---- scalar aggregation for output layer ---------------------------------
__global__ void k_agg_scalar(const float* __restrict__ h3, const float* __restrict__ dis,
                             const int* __restrict__ rowptr, const int2* __restrict__ csr_sn,
                             const float* __restrict__ b3, float* __restrict__ out) {
    int n = blockIdx.x * blockDim.x + threadIdx.x;
    if (n >= NNODES) return;
    float d = dis[n];
    float acc = h3[n] * d * d;
    int beg = rowptr[n], end = rowptr[n + 1];
    for (int i = beg; i < end; i++) {
        int2 sn2 = csr_sn[i];
        acc += h3[sn2.x] * __int_as_float(sn2.y);
    }
    out[n] = acc + b3[0];
}

extern "C" void kernel_launch(void* const* d_in, const int* in_sizes, int n_in,
                              void* d_out, int out_size, void* d_ws, size_t ws_size,
                              hipStream_t stream) {
    const float* x  = (const float*)d_in[0];
    const int*   ei = (const int*)d_in[1];
    const float* ea = (const float*)d_in[2];
    const float* g  = (const float*)d_in[3];
    const float* be = (const float*)d_in[4];
    const float* W1 = (const float*)d_in[5];
    const float* b1 = (const float*)d_in[6];
    const float* W2 = (const float*)d_in[7];
    const float* b2 = (const float*)d_in[8];
    const float* W3 = (const float*)d_in[9];
    const float* b3 = (const float*)d_in[10];
    float* out = (float*)d_out;

    char* ws = (char*)d_ws;
    size_t off = 0;
    auto alloc = [&](size_t bytes) {
        void* p = ws + off;
        off += (bytes + 255) & ~((size_t)255);
        return p;
    };
    float* bufA     = (float*)alloc((size_t)NNODES * NF * 4);
    float* bufB     = (float*)alloc((size_t)NNODES * NF * 4);
    float* bufC     = (float*)alloc((size_t)NNODES * NF * 4);
    float* ew       = (float*)alloc((size_t)NEDGES * 4);
    int*   rank     = (int*)  alloc((size_t)NEDGES * 4);
    float* dis      = (float*)alloc((size_t)NNODES * 4);
    int*   cnt      = (int*)  alloc((size_t)NNODES * 4);
    int*   rowptr   = (int*)  alloc((size_t)(NNODES + 1) * 4);
    int2*  csr_sw   = (int2*) alloc((size_t)NEDGES * 8);
    int2*  csr_sn   = (int2*) alloc((size_t)NEDGES * 8);
    int*   bsum     = (int*)  alloc(256 * 4);
    float* h3       = (float*)alloc((size_t)NNODES * 4);
    (void)ws_size; (void)in_sizes; (void)n_in; (void)out_size;

    const int NB_N = (NNODES + 255) / 256;      // 196
    const int NB_E = (NEDGES + 255) / 256;      // 3125
    const int NB_W = (NNODES * 64 + 255) / 256; // 12500 (wave per node)
    const int NB_G = (NNODES + 63) / 64;        // 782  (gemm 64-row tiles)

    k_init<<<NB_N, 256, 0, stream>>>(cnt);
    k_count_rank<<<NB_E, 256, 0, stream>>>(ei, ea, ew, rank, cnt);
    k_scan1<<<NB_N, 256, 0, stream>>>(cnt, bsum);
    k_scan2<<<1, 256, 0, stream>>>(bsum, NB_N);
    k_scan3<<<NB_N, 256, 0, stream>>>(cnt, bsum, rowptr);
    k_scatter<<<NB_E, 256, 0, stream>>>(ei, ew, rank, rowptr, csr_sw);
    k_deg_dis<<<NB_N, 256, 0, stream>>>(csr_sw, rowptr, dis);
    k_csr_norm<<<NB_N, 256, 0, stream>>>(csr_sw, rowptr, dis, csr_sn);

    k_layernorm<<<NB_W, 256, 0, stream>>>(x, g, be, bufA);

    // layer 1
    k_gemm128<<<NB_G, 256, 0, stream>>>(bufA, W1, bufB, NNODES);
    k_aggregate<true><<<NB_W, 256, 0, stream>>>(bufB, dis, rowptr, csr_sn, b1, bufC);
    // layer 2
    k_gemm128<<<NB_G, 256, 0, stream>>>(bufC, W2, bufA, NNODES);
    k_aggregate<true><<<NB_W, 256, 0, stream>>>(bufA, dis, rowptr, csr_sn, b2, bufB);
    // layer 3
    k_gemv128<<<NB_W, 256, 0, stream>>>(bufB, W3, h3);
    k_agg_scalar<<<NB_N, 256, 0, stream>>>(h3, dis, rowptr, csr_sn, b3, out);
}

// Round 3
// 375.707 us; speedup vs baseline: 1.2105x; 1.0570x over previous
//
#include <hip/hip_runtime.h>
#include <math.h>

#define NNODES 50000
#define NEDGES 800000
#define NF 128
constexpr float LN_EPS = 1e-5f;

__device__ __forceinline__ float clean0(float v) {
    return (isnan(v) || isinf(v)) ? 0.0f : v;
}
__device__ __forceinline__ float cleanw(float v) {
    if (isnan(v)) return 0.0f;
    if (isinf(v)) return v > 0.0f ? 1.0f : 0.0f;
    return v;
}
__device__ __forceinline__ int clampN(int v) {
    return min(max(v, 0), NNODES - 1);
}

// ---- init: cnt=0 ---------------------------------------------------------
__global__ void k_init(int* cnt) {
    int i = blockIdx.x * blockDim.x + threadIdx.x;
    if (i < NNODES) cnt[i] = 0;
}

// ---- pass 1: clean weight, count in-degree, record per-edge rank ---------
__global__ void k_count_rank(const int* __restrict__ ei, const float* __restrict__ ea,
                             float* __restrict__ ew, int* __restrict__ rank,
                             int* __restrict__ cnt) {
    int e = blockIdx.x * blockDim.x + threadIdx.x;
    if (e >= NEDGES) return;
    int c = clampN(ei[NEDGES + e]);
    ew[e] = cleanw(ea[e]);
    rank[e] = atomicAdd(&cnt[c], 1);
}

// ---- 3-kernel exclusive scan of cnt[N] -> rowptr[N+1] --------------------
__global__ void k_scan1(const int* __restrict__ cnt, int* __restrict__ bsum) {
    __shared__ int sm[256];
    int t = threadIdx.x;
    int i = blockIdx.x * 256 + t;
    sm[t] = (i < NNODES) ? cnt[i] : 0;
    __syncthreads();
    for (int o = 128; o > 0; o >>= 1) {
        if (t < o) sm[t] += sm[t + o];
        __syncthreads();
    }
    if (t == 0) bsum[blockIdx.x] = sm[0];
}

__global__ void k_scan2(int* __restrict__ bsum, int nb) {
    __shared__ int sm[256];
    int t = threadIdx.x;
    int v = (t < nb) ? bsum[t] : 0;
    sm[t] = v;
    __syncthreads();
    for (int o = 1; o < 256; o <<= 1) {
        int add = (t >= o) ? sm[t - o] : 0;
        __syncthreads();
        sm[t] += add;
        __syncthreads();
    }
    if (t < nb) bsum[t] = sm[t] - v;   // exclusive
}

__global__ void k_scan3(const int* __restrict__ cnt, const int* __restrict__ bsum,
                        int* __restrict__ rowptr) {
    __shared__ int sm[256];
    int t = threadIdx.x;
    int i = blockIdx.x * 256 + t;
    int v = (i < NNODES) ? cnt[i] : 0;
    sm[t] = v;
    __syncthreads();
    for (int o = 1; o < 256; o <<= 1) {
        int add = (t >= o) ? sm[t - o] : 0;
        __syncthreads();
        sm[t] += add;
        __syncthreads();
    }
    if (i < NNODES) rowptr[i + 1] = bsum[blockIdx.x] + sm[t];  // inclusive + base
    if (i == 0) rowptr[0] = 0;
}

// ---- pass 2: atomic-free scatter into CSR, packed (src, w) 8B ------------
__global__ void k_scatter(const int* __restrict__ ei, const float* __restrict__ ew,
                          const int* __restrict__ rank, const int* __restrict__ rowptr,
                          int2* __restrict__ csr_sw) {
    int e = blockIdx.x * blockDim.x + threadIdx.x;
    if (e >= NEDGES) return;
    int r = clampN(ei[e]);
    int c = clampN(ei[NEDGES + e]);
    int pos = rowptr[c] + rank[e];
    csr_sw[pos] = make_int2(r, __float_as_int(ew[e]));
}

// ---- deg by row-gather (no atomics), dis = rsqrt(deg) --------------------
__global__ void k_deg_dis(const int2* __restrict__ csr_sw, const int* __restrict__ rowptr,
                          float* __restrict__ dis) {
    int n = blockIdx.x * blockDim.x + threadIdx.x;
    if (n >= NNODES) return;
    int beg = rowptr[n], end = rowptr[n + 1];
    float d = 1.0f;                      // self-loop weight
    for (int p = beg; p < end; p++) d += __int_as_float(csr_sw[p].y);
    dis[n] = (d > 0.0f) ? rsqrtf(d) : 0.0f;
}

// ---- csr_norm packed (src, dis[src]*w*dis[n]) ----------------------------
__global__ void k_csr_norm(const int2* __restrict__ csr_sw, const int* __restrict__ rowptr,
                           const float* __restrict__ dis, int2* __restrict__ csr_sn) {
    int n = blockIdx.x * blockDim.x + threadIdx.x;
    if (n >= NNODES) return;
    int beg = rowptr[n], end = rowptr[n + 1];
    float dn = dis[n];
    for (int p = beg; p < end; p++) {
        int2 sw = csr_sw[p];
        float nm = dis[sw.x] * __int_as_float(sw.y) * dn;
        csr_sn[p] = make_int2(sw.x, __float_as_int(nm));
    }
}

// ---- LayerNorm: one wave per node, float2 per lane -----------------------
__global__ void k_layernorm(const float* __restrict__ x, const float* __restrict__ gamma,
                            const float* __restrict__ beta, float* __restrict__ xn) {
    int n = (blockIdx.x * blockDim.x + threadIdx.x) >> 6;
    int lane = threadIdx.x & 63;
    if (n >= NNODES) return;
    float2 v = ((const float2*)(x + (size_t)n * NF))[lane];
    v.x = clean0(v.x); v.y = clean0(v.y);
    float s = v.x + v.y;
    for (int o = 32; o > 0; o >>= 1) s += __shfl_xor(s, o);
    float mu = s * (1.0f / NF);
    float dx = v.x - mu, dy = v.y - mu;
    float q = dx * dx + dy * dy;
    for (int o = 32; o > 0; o >>= 1) q += __shfl_xor(q, o);
    float rstd = rsqrtf(q * (1.0f / NF) + LN_EPS);
    float2 g = ((const float2*)gamma)[lane];
    float2 b = ((const float2*)beta)[lane];
    float2 o2;
    o2.x = dx * rstd * g.x + b.x;
    o2.y = dy * rstd * g.y + b.y;
    ((float2*)(xn + (size_t)n * NF))[lane] = o2;
}

// ---- fp32 GEMM: C[M,128] = A[M,128] @ W[128,128] -------------------------
__global__ __launch_bounds__(256) void k_gemm128(const float* __restrict__ A,
                                                 const float* __restrict__ W,
                                                 float* __restrict__ C, int M) {
    __shared__ float xs[64][129];
    __shared__ float ws[32][128];
    int t = threadIdx.x;
    int row0 = blockIdx.x * 64;

    for (int i = 0; i < 8; i++) {
        int j = t + i * 256;
        int r = j >> 5;
        int c4 = (j & 31) * 4;
        int gr = row0 + r;
        float4 v = make_float4(0.f, 0.f, 0.f, 0.f);
        if (gr < M) v = *(const float4*)(A + (size_t)gr * 128 + c4);
        xs[r][c4 + 0] = v.x; xs[r][c4 + 1] = v.y; xs[r][c4 + 2] = v.z; xs[r][c4 + 3] = v.w;
    }

    int tx = t & 31, ty = t >> 5;
    int c0 = tx * 4, r0 = ty * 8;
    float acc[8][4];
    #pragma unroll
    for (int j = 0; j < 8; j++)
        for (int q = 0; q < 4; q++) acc[j][q] = 0.0f;

    for (int kk = 0; kk < 4; kk++) {
        __syncthreads();
        for (int i = 0; i < 4; i++) {
            int j = t + i * 256;
            int r = j >> 5;
            int c4 = (j & 31) * 4;
            *(float4*)&ws[r][c4] = *(const float4*)(W + (size_t)(kk * 32 + r) * 128 + c4);
        }
        __syncthreads();
        #pragma unroll
        for (int k2 = 0; k2 < 32; k2++) {
            float4 wv = *(const float4*)&ws[k2][c0];
            int kg = kk * 32 + k2;
            #pragma unroll
            for (int j = 0; j < 8; j++) {
                float a = xs[r0 + j][kg];
                acc[j][0] += a * wv.x;
                acc[j][1] += a * wv.y;
                acc[j][2] += a * wv.z;
                acc[j][3] += a * wv.w;
            }
        }
    }

    #pragma unroll
    for (int j = 0; j < 8; j++) {
        int gr = row0 + r0 + j;
        if (gr < M) {
            float4 v = make_float4(acc[j][0], acc[j][1], acc[j][2], acc[j][3]);
            *(float4*)(C + (size_t)gr * 128 + c0) = v;
        }
    }
}

// ---- CSR aggregation: one wave per node --------------------------------
// n forced uniform (readfirstlane) so (src,norm) records load via s_load;
// edge loop unrolled x8 so 8 independent 512B row-gathers are in flight.
template <bool RELU>
__global__ void k_aggregate(const float* __restrict__ h, const float* __restrict__ dis,
                            const int* __restrict__ rowptr, const int2* __restrict__ csr_sn,
                            const float* __restrict__ bias, float* __restrict__ out) {
    int n0 = (blockIdx.x * blockDim.x + threadIdx.x) >> 6;
    if (n0 >= NNODES) return;
    int n = __builtin_amdgcn_readfirstlane(n0);
    int lane = threadIdx.x & 63;
    float d = dis[n];
    float sn = d * d;
    float2 acc = ((const float2*)(h + (size_t)n * NF))[lane];
    acc.x *= sn; acc.y *= sn;
    int beg = rowptr[n], end = rowptr[n + 1];
    int p = beg;
    for (; p + 8 <= end; p += 8) {
        int2 e[8];
        #pragma unroll
        for (int j = 0; j < 8; j++) e[j] = csr_sn[p + j];
        float2 v[8];
        #pragma unroll
        for (int j = 0; j < 8; j++)
            v[j] = *((const float2*)(h + (size_t)e[j].x * NF) + lane);
        #pragma unroll
        for (int j = 0; j < 8; j++) {
            float w = __int_as_float(e[j].y);
            acc.x += v[j].x * w;
            acc.y += v[j].y * w;
        }
    }
    for (; p + 2 <= end; p += 2) {
        int2 e0 = csr_sn[p], e1 = csr_sn[p + 1];
        float2 v0 = *((const float2*)(h + (size_t)e0.x * NF) + lane);
        float2 v1 = *((const float2*)(h + (size_t)e1.x * NF) + lane);
        float w0 = __int_as_float(e0.y), w1 = __int_as_float(e1.y);
        acc.x += v0.x * w0 + v1.x * w1;
        acc.y += v0.y * w0 + v1.y * w1;
    }
    if (p < end) {
        int2 e = csr_sn[p];
        float2 v = *((const float2*)(h + (size_t)e.x * NF) + lane);
        float w = __int_as_float(e.y);
        acc.x += v.x * w;
        acc.y += v.y * w;
    }
    float2 b = ((const float2*)bias)[lane];
    acc.x += b.x; acc.y += b.y;
    if (RELU) { acc.x = fmaxf(acc.x, 0.0f); acc.y = fmaxf(acc.y, 0.0f); }
    ((float2*)(out + (size_t)n * NF))[lane] = acc;
}

// ---- GEMV: h3[n] = dot(X[n,:], W3[:,0]) ----------------------------------
__global__ void k_gemv128(const float* __restrict__ X, const float* __restrict__ W3,
                          float* __restrict__ h3) {
    int n = (blockIdx.x * blockDim.x + threadIdx.x) >> 6;
    int lane = threadIdx.x & 63;
    if (n >= NNODES) return;
    float2 v = ((const float2*)(X + (size_t)n * NF))[lane];
    float2 w = ((const float2*)W3)[lane];
    float s = v.x * w.x + v.y * w.y;
    for (int o = 32; o > 0; o >>= 1) s += __shfl_xor(s, o);
    if (lane == 0) h3[n] = s;
}

// ---- scalar aggregation for output layer ---------------------------------
__global__ void k_agg_scalar(const float* __restrict__ h3, const float* __restrict__ dis,
                             const int* __restrict__ rowptr, const int2* __restrict__ csr_sn,
                             const float* __restrict__ b3, float* __restrict__ out) {
    int n = blockIdx.x * blockDim.x + threadIdx.x;
    if (n >= NNODES) return;
    float d = dis[n];
    float acc = h3[n] * d * d;
    int beg = rowptr[n], end = rowptr[n + 1];
    int p = beg;
    for (; p + 4 <= end; p += 4) {
        int2 e0 = csr_sn[p], e1 = csr_sn[p + 1], e2 = csr_sn[p + 2], e3 = csr_sn[p + 3];
        float v0 = h3[e0.x], v1 = h3[e1.x], v2 = h3[e2.x], v3 = h3[e3.x];
        acc += v0 * __int_as_float(e0.y) + v1 * __int_as_float(e1.y)
             + v2 * __int_as_float(e2.y) + v3 * __int_as_float(e3.y);
    }
    for (; p < end; p++) {
        int2 e = csr_sn[p];
        acc += h3[e.x] * __int_as_float(e.y);
    }
    out[n] = acc + b3[0];
}

extern "C" void kernel_launch(void* const* d_in, const int* in_sizes, int n_in,
                              void* d_out, int out_size, void* d_ws, size_t ws_size,
                              hipStream_t stream) {
    const float* x  = (const float*)d_in[0];
    const int*   ei = (const int*)d_in[1];
    const float* ea = (const float*)d_in[2];
    const float* g  = (const float*)d_in[3];
    const float* be = (const float*)d_in[4];
    const float* W1 = (const float*)d_in[5];
    const float* b1 = (const float*)d_in[6];
    const float* W2 = (const float*)d_in[7];
    const float* b2 = (const float*)d_in[8];
    const float* W3 = (const float*)d_in[9];
    const float* b3 = (const float*)d_in[10];
    float* out = (float*)d_out;

    char* ws = (char*)d_ws;
    size_t off = 0;
    auto alloc = [&](size_t bytes) {
        void* p = ws + off;
        off += (bytes + 255) & ~((size_t)255);
        return p;
    };
    float* bufA     = (float*)alloc((size_t)NNODES * NF * 4);
    float* bufB     = (float*)alloc((size_t)NNODES * NF * 4);
    float* bufC     = (float*)alloc((size_t)NNODES * NF * 4);
    float* ew       = (float*)alloc((size_t)NEDGES * 4);
    int*   rank     = (int*)  alloc((size_t)NEDGES * 4);
    float* dis      = (float*)alloc((size_t)NNODES * 4);
    int*   cnt      = (int*)  alloc((size_t)NNODES * 4);
    int*   rowptr   = (int*)  alloc((size_t)(NNODES + 1) * 4);
    int2*  csr_sw   = (int2*) alloc((size_t)NEDGES * 8);
    int2*  csr_sn   = (int2*) alloc((size_t)NEDGES * 8);
    int*   bsum     = (int*)  alloc(256 * 4);
    float* h3       = (float*)alloc((size_t)NNODES * 4);
    (void)ws_size; (void)in_sizes; (void)n_in; (void)out_size;

    const int NB_N = (NNODES + 255) / 256;      // 196
    const int NB_E = (NEDGES + 255) / 256;      // 3125
    const int NB_W = (NNODES * 64 + 255) / 256; // 12500 (wave per node)
    const int NB_G = (NNODES + 63) / 64;        // 782  (gemm 64-row tiles)

    k_init<<<NB_N, 256, 0, stream>>>(cnt);
    k_count_rank<<<NB_E, 256, 0, stream>>>(ei, ea, ew, rank, cnt);
    k_scan1<<<NB_N, 256, 0, stream>>>(cnt, bsum);
    k_scan2<<<1, 256, 0, stream>>>(bsum, NB_N);
    k_scan3<<<NB_N, 256, 0, stream>>>(cnt, bsum, rowptr);
    k_scatter<<<NB_E, 256, 0, stream>>>(ei, ew, rank, rowptr, csr_sw);
    k_deg_dis<<<NB_N, 256, 0, stream>>>(csr_sw, rowptr, dis);
    k_csr_norm<<<NB_N, 256, 0, stream>>>(csr_sw, rowptr, dis, csr_sn);

    k_layernorm<<<NB_W, 256, 0, stream>>>(x, g, be, bufA);

    // layer 1
    k_gemm128<<<NB_G, 256, 0, stream>>>(bufA, W1, bufB, NNODES);
    k_aggregate<true><<<NB_W, 256, 0, stream>>>(bufB, dis, rowptr, csr_sn, b1, bufC);
    // layer 2
    k_gemm128<<<NB_G, 256, 0, stream>>>(bufC, W2, bufA, NNODES);
    k_aggregate<true><<<NB_W, 256, 0, stream>>>(bufA, dis, rowptr, csr_sn, b2, bufB);
    // layer 3
    k_gemv128<<<NB_W, 256, 0, stream>>>(bufB, W3, h3);
    k_agg_scalar<<<NB_N, 256, 0, stream>>>(h3, dis, rowptr, csr_sn, b3, out);
}